// Round 11
// baseline (232.751 us; speedup 1.0000x reference)
//
#include <hip/hip_runtime.h>
#include <hip/hip_bf16.h>

#define Nn 16384
#define Dd 256
#define L2E 1.4426950408889634f
#define LN2 0.6931471805599453f

typedef __attribute__((ext_vector_type(8))) int int8v;
typedef __attribute__((ext_vector_type(16))) float f32x16;

__device__ inline void gload_lds16(const void* g, void* l) {
    __builtin_amdgcn_global_load_lds(
        (const __attribute__((address_space(1))) void*)g,
        (__attribute__((address_space(3))) void*)l, 16, 0, 0);
}

// fp32 -> fp8 e4m3 (HW RNE). A pre-scaled by log2e: epilogue softplus works in
// exp2/log2 domain with no per-element muls.
__global__ __launch_bounds__(256) void cvt_kernel(
        const float4* __restrict__ a, const float4* __restrict__ b,
        int2* __restrict__ oa, int2* __restrict__ ob) {
    int i = blockIdx.x * 256 + threadIdx.x;
    float4 a0 = a[2 * i], a1 = a[2 * i + 1];
    float4 b0 = b[2 * i], b1 = b[2 * i + 1];
    int alo = __builtin_amdgcn_cvt_pk_fp8_f32(a0.x * L2E, a0.y * L2E, 0, false);
    alo     = __builtin_amdgcn_cvt_pk_fp8_f32(a0.z * L2E, a0.w * L2E, alo, true);
    int ahi = __builtin_amdgcn_cvt_pk_fp8_f32(a1.x * L2E, a1.y * L2E, 0, false);
    ahi     = __builtin_amdgcn_cvt_pk_fp8_f32(a1.z * L2E, a1.w * L2E, ahi, true);
    int blo = __builtin_amdgcn_cvt_pk_fp8_f32(b0.x, b0.y, 0, false);
    blo     = __builtin_amdgcn_cvt_pk_fp8_f32(b0.z, b0.w, blo, true);
    int bhi = __builtin_amdgcn_cvt_pk_fp8_f32(b1.x, b1.y, 0, false);
    bhi     = __builtin_amdgcn_cvt_pk_fp8_f32(b1.z, b1.w, bhi, true);
    oa[i] = make_int2(alo, ahi);
    ob[i] = make_int2(blo, bhi);
}

// 2x ds_read_b128 of one lane's 32 contiguous K-bytes from a [rows][256B]
// full-K LDS tile, XOR-deswizzled (16 chunks/row, chunk ^= row&15).
// Measured ZERO bank conflicts (R8/R9/R10).
__device__ inline int8v read_frag256(const unsigned char* base, int rr, int cb) {
    int x = rr & 15;
    int4 lo = *(const int4*)&base[rr * 256 + ((cb ^ x) * 16)];
    int4 hi = *(const int4*)&base[rr * 256 + (((cb + 1) ^ x) * 16)];
    int8v r;
    r[0] = lo.x; r[1] = lo.y; r[2] = lo.z; r[3] = lo.w;
    r[4] = hi.x; r[5] = hi.y; r[6] = hi.z; r[7] = hi.w;
    return r;
}

// Fused MX-fp8 GEMM (sim' = log2e * za.zb^T, unit e8m0 scales) + siglip loss.
// R10's straight-line block at HALF size for co-residency: tile 128x128,
// 256 thr = 4 waves (2M x 2N, wave tile 64x64 -> acc[2][2], same register
// shape as no-spill R10: ~116 VGPR + 64 AGPR = 180 unified/wave).
// LDS 64KB/block -> 2 blocks/CU by LDS AND registers (2 waves/SIMD x 180 =
// 360 <= 512; R7's 512-thr attempt needed 4/SIMD = 720 > 512, which is why
// co-residency never happened). One block's stage-wait/epilogue hides under
// the other's MFMAs.
__global__ __launch_bounds__(256, 2) void siglip_kernel(
        const unsigned char* __restrict__ ga,   // za*log2e fp8 [16384][256]
        const unsigned char* __restrict__ gb,   // zb fp8 [16384][256]
        const float* __restrict__ bp,           // bias scalar
        float* __restrict__ out) {
    __shared__ unsigned char As[128 * 256];   // 32 KB, full-K A tile
    __shared__ unsigned char Bs[128 * 256];   // 32 KB, full-K B tile
    __shared__ float wsum[4];

    const int tid  = threadIdx.x;
    const int lane = tid & 63;
    const int wid  = tid >> 6;     // 0..3
    const int wm   = wid >> 1;     // 0..1 -> 64-row slice of the 128-row tile
    const int wn   = wid & 1;      // 0..1 -> 64-col slice of the 128-col tile
    const int l31  = lane & 31;
    const int h    = lane >> 5;

    // XCD-chunked swizzle + 8x8 supertile (grid 16384 = 8 XCD x 2048).
    const int bid = blockIdx.x;
    const int nid = (bid & 7) * 2048 + (bid >> 3);
    const int sc  = nid >> 6, sl = nid & 63;     // supertile 0..255, local 0..63
    const int by  = (sc >> 4) * 8 + (sl >> 3);   // 0..127 (M/128)
    const int bx  = (sc & 15) * 8 + (sl & 7);    // 0..127 (N/128)
    const size_t rowA0 = (size_t)by * 128;
    const size_t rowB0 = (size_t)bx * 128;

    const float b2 = bp[0] * L2E;

    // ---- stage full-K A+B tiles ONCE: 16 loads/thread ----
    // source chunk pre-swizzled ((c&15)^(row&15)) so read_frag256's XOR'd
    // ds_read_b128 deswizzles correctly (bank-conflict-free, proven).
#pragma unroll
    for (int p = 0; p < 8; ++p) {
        int c = p * 256 + tid; int row = c >> 4;
        int scl = (c & 15) ^ (row & 15);
        gload_lds16(&ga[(rowA0 + row) * Dd + scl * 16], &As[c * 16]);
    }
#pragma unroll
    for (int p = 0; p < 8; ++p) {
        int c = p * 256 + tid; int row = c >> 4;
        int scl = (c & 15) ^ (row & 15);
        gload_lds16(&gb[(rowB0 + row) * Dd + scl * 16], &Bs[c * 16]);
    }

    // bias folded into MFMA C operand: acc ends as y = s' - b2
    f32x16 acc[2][2];
#pragma unroll
    for (int mf = 0; mf < 2; ++mf)
#pragma unroll
        for (int nf = 0; nf < 2; ++nf)
#pragma unroll
            for (int q = 0; q < 16; ++q) acc[mf][nf][q] = -b2;

    asm volatile("s_waitcnt vmcnt(0)" ::: "memory");
    __builtin_amdgcn_s_barrier();
    asm volatile("" ::: "memory");

    // ---- K = 256 in 4 s-steps of 64B, straight-line, 16 MFMAs/wave ----
#pragma unroll
    for (int s = 0; s < 4; ++s) {
        int cb = s * 4 + h * 2;
        int8v aF0 = read_frag256(As, wm * 64 + l31, cb);
        int8v aF1 = read_frag256(As, wm * 64 + 32 + l31, cb);
        int8v bF0 = read_frag256(Bs, wn * 64 + l31, cb);
        int8v bF1 = read_frag256(Bs, wn * 64 + 32 + l31, cb);
        acc[0][0] = __builtin_amdgcn_mfma_scale_f32_32x32x64_f8f6f4(
            aF0, bF0, acc[0][0], 0, 0, 0, 0x7F7F7F7F, 0, 0x7F7F7F7F);
        acc[0][1] = __builtin_amdgcn_mfma_scale_f32_32x32x64_f8f6f4(
            aF0, bF1, acc[0][1], 0, 0, 0, 0x7F7F7F7F, 0, 0x7F7F7F7F);
        acc[1][0] = __builtin_amdgcn_mfma_scale_f32_32x32x64_f8f6f4(
            aF1, bF0, acc[1][0], 0, 0, 0, 0x7F7F7F7F, 0, 0x7F7F7F7F);
        acc[1][1] = __builtin_amdgcn_mfma_scale_f32_32x32x64_f8f6f4(
            aF1, bF1, acc[1][1], 0, 0, 0, 0x7F7F7F7F, 0, 0x7F7F7F7F);
    }
    // no trailing barrier: waves desync into the VALU/trans epilogue.

    // ---- epilogue: nats/elem = ln2*max(y,0) + ln(1+2^-|y|) ~= ln2*r1 + e
    // (dropping e^2/2: mean bias ~ -0.007; R10 absmax 0.031 << 0.128) ----
    float r1 = 0.f, r2 = 0.f, ld = 0.f;
#pragma unroll
    for (int mf = 0; mf < 2; ++mf)
#pragma unroll
        for (int nf = 0; nf < 2; ++nf)
#pragma unroll
            for (int q = 0; q < 16; ++q) {
                float y = acc[mf][nf][q];
                r1 += fmaxf(y, 0.f);
                r2 += __builtin_amdgcn_exp2f(-fabsf(y));
            }

    // Diagonal correction on the 128 bx==by blocks.
    if (bx == by) {
#pragma unroll
        for (int mf = 0; mf < 2; ++mf)
#pragma unroll
            for (int nf = 0; nf < 2; ++nf)
#pragma unroll
                for (int q = 0; q < 16; ++q) {
                    int i_loc = wm * 64 + mf * 32 + (q & 3) + 8 * (q >> 2) + 4 * h;
                    int j_loc = wn * 64 + nf * 32 + l31;
                    if (i_loc == j_loc) {
                        float y  = acc[mf][nf][q];
                        float u  = -(y + 2.f * b2);
                        float ey = __builtin_amdgcn_exp2f(-fabsf(y));
                        float eu = __builtin_amdgcn_exp2f(-fabsf(u));
                        float off = LN2 * fmaxf(y, 0.f) + ey;
                        float dg  = LN2 * fmaxf(u, 0.f) + eu;
                        ld += dg - off;
                    }
                }
    }

    float v = fmaf(LN2, r1, r2) + ld;   // nats

    // wave reduce then block reduce
#pragma unroll
    for (int off = 32; off; off >>= 1)
        v += __shfl_down(v, off);
    if (lane == 0) wsum[wid] = v;
    __syncthreads();
    if (tid == 0) {
        float t = wsum[0] + wsum[1] + wsum[2] + wsum[3];
        atomicAdd(out, t * (1.0f / ((float)Nn * (float)Nn)));
    }
}

extern "C" void kernel_launch(void* const* d_in, const int* in_sizes, int n_in,
                              void* d_out, int out_size, void* d_ws, size_t ws_size,
                              hipStream_t stream) {
    const float* za   = (const float*)d_in[0];
    const float* zb   = (const float*)d_in[1];
    const float* bias = (const float*)d_in[2];

    unsigned char* wa = (unsigned char*)d_ws;
    unsigned char* wb = wa + (size_t)Nn * Dd;

    // zero the output accumulator (harness does not re-poison between replays)
    hipMemsetAsync(d_out, 0, sizeof(float), stream);

    // fp32 -> fp8 pre-pass (A pre-scaled by log2e)
    cvt_kernel<<<dim3(Nn * Dd / 2048), 256, 0, stream>>>(
        (const float4*)za, (const float4*)zb, (int2*)wa, (int2*)wb);

    // fused GEMM + loss: grid 128 x 128 = 16384 blocks
    siglip_kernel<<<dim3(16384), 256, 0, stream>>>(wa, wb, bias, (float*)d_out);
}